// Round 3
// baseline (626.178 us; speedup 1.0000x reference)
//
#include <hip/hip_runtime.h>
#include <math.h>

// Problem constants
#define NB   32768
#define AG   6
#define LL   225
#define DD   128
#define EE   5
#define NOUT 5
#define ADIM 64

// Workspace layout (floats)
#define WS_M   0        // 128*128  : M = q_w @ k_w^T / 8   (row-major [d1][d2])
#define WS_W1T 16384    // 5*128    : W1t[o*128+d] = sum_e fc_w[(e*128+d)*5+o]
#define WS_F2T 17024    // 25*128   : F2t[(e*5+o)*128+d] = fc_w[(640+e*128+d)*5+o]

// Tiling: block = 256 thr = 4 waves; wave = 8 samples (8 groups x 8 lanes);
// lane owns 16 cols: {32k + 4i .. 32k+4i+3}, k=0..3, i=lane&7.
#define SBLK 32          // samples per block
#define RWS  (SBLK*AG)   // 192 obs rows per block
#define LC   28          // l-chunk; 8 chunks cover l=0..223, l=224 is the tail
#define NCH  8
#define ENCW_OFF 5376    // 192*28
#define LDS_FLOATS 8960  // 5376 + 28*128 = 35.84 KB -> LDS allows 4 blk/CU (VGPR caps at 3)

__global__ void precompute_kernel(const float* __restrict__ q_w,
                                  const float* __restrict__ k_w,
                                  const float* __restrict__ fc_w,
                                  float* __restrict__ ws) {
    int b = blockIdx.x;
    int t = threadIdx.x;
    if (b < 128) {
        float s = 0.f;
        #pragma unroll 8
        for (int j = 0; j < ADIM; ++j)
            s = fmaf(q_w[b * ADIM + j], k_w[t * ADIM + j], s);
        ws[WS_M + b * 128 + t] = s * 0.125f;
    } else {
        int d = t;
        #pragma unroll
        for (int o = 0; o < NOUT; ++o) {
            float s = 0.f;
            #pragma unroll
            for (int e = 0; e < EE; ++e)
                s += fc_w[(e * 128 + d) * NOUT + o];
            ws[WS_W1T + o * 128 + d] = s;
            #pragma unroll
            for (int e = 0; e < EE; ++e)
                ws[WS_F2T + (e * 5 + o) * 128 + d] = fc_w[(640 + e * 128 + d) * NOUT + o];
        }
    }
}

__global__ __launch_bounds__(256, 3)
void policy_kernel(const float* __restrict__ obs,
                   const float* __restrict__ enc_w,
                   const float* __restrict__ enc_b,
                   const float* __restrict__ fc_b,
                   const float* __restrict__ u,
                   const float* __restrict__ ws,
                   int* __restrict__ out) {
    __shared__ float lds[LDS_FLOATS];
    const int tid  = threadIdx.x;
    const int lane = tid & 63;
    const int w    = tid >> 6;
    const int g    = lane >> 3;      // sample group 0..7
    const int i    = lane & 7;       // col sub-index
    const int bs0  = blockIdx.x * SBLK;
    const int samp = w * 8 + g;      // block-local sample
    const int obsrow = samp * AG;    // block-local obs row of agent 0

    float acc[AG][16];
    #pragma unroll
    for (int a = 0; a < AG; ++a)
        #pragma unroll
        for (int c = 0; c < 16; ++c) acc[a][c] = 0.f;

    const float* obs_blk = obs + (size_t)bs0 * (AG * LL);

    #pragma unroll 1
    for (int ch = 0; ch < NCH; ++ch) {
        const int l0 = ch * LC;
        // ---- stage obs chunk: 192 rows x 28 cols; lds[idx] with idx == row*28+col ----
        #pragma unroll
        for (int k = 0; k < 21; ++k) {           // 5376 = 21*256, no mask needed
            int idx = tid + k * 256;
            int row = idx / LC;                  // magic-mul div
            int col = idx - row * LC;
            lds[idx] = obs_blk[row * LL + l0 + col];
        }
        // ---- stage enc_w chunk: 28 x 128 floats (coalesced float4) ----
        {
            const float4* src = (const float4*)(enc_w + (size_t)l0 * DD);
            #pragma unroll
            for (int k = 0; k < 4; ++k) {
                int idx = tid + k * 256;
                if (idx < (LC * DD) / 4)
                    *(float4*)&lds[ENCW_OFF + idx * 4] = src[idx];
            }
        }
        __syncthreads();

        // ---- compute: 7 l-quads ----
        #pragma unroll 1
        for (int q = 0; q < 7; ++q) {
            const int lq = 4 * q;
            float ew[4][16];
            #pragma unroll
            for (int dl = 0; dl < 4; ++dl)
                #pragma unroll
                for (int k = 0; k < 4; ++k) {
                    float4 t4 = *(const float4*)&lds[ENCW_OFF + (lq + dl) * DD + 32 * k + 4 * i];
                    ew[dl][4 * k + 0] = t4.x; ew[dl][4 * k + 1] = t4.y;
                    ew[dl][4 * k + 2] = t4.z; ew[dl][4 * k + 3] = t4.w;
                }
            #pragma unroll
            for (int a = 0; a < AG; ++a) {
                float4 ov4 = *(const float4*)&lds[(obsrow + a) * LC + lq];
                float ov[4] = {ov4.x, ov4.y, ov4.z, ov4.w};
                #pragma unroll
                for (int dl = 0; dl < 4; ++dl)
                    #pragma unroll
                    for (int c = 0; c < 16; ++c)
                        acc[a][c] = fmaf(ov[dl], ew[dl][c], acc[a][c]);
            }
        }
        __syncthreads();
    }

    // ---- tail l = 224 (straight from global; enc_w row is L2-hot) ----
    {
        float ewt[16];
        #pragma unroll
        for (int k = 0; k < 4; ++k) {
            float4 t4 = *(const float4*)&enc_w[(size_t)224 * DD + 32 * k + 4 * i];
            ewt[4 * k + 0] = t4.x; ewt[4 * k + 1] = t4.y;
            ewt[4 * k + 2] = t4.z; ewt[4 * k + 3] = t4.w;
        }
        #pragma unroll
        for (int a = 0; a < AG; ++a) {
            float ov = obs_blk[(obsrow + a) * LL + 224];
            #pragma unroll
            for (int c = 0; c < 16; ++c)
                acc[a][c] = fmaf(ov, ewt[c], acc[a][c]);
        }
    }

    // ---- bias + relu in place ----
    #pragma unroll
    for (int k = 0; k < 4; ++k) {
        float4 b4 = *(const float4*)&enc_b[32 * k + 4 * i];
        #pragma unroll
        for (int a = 0; a < AG; ++a) {
            acc[a][4 * k + 0] = fmaxf(acc[a][4 * k + 0] + b4.x, 0.f);
            acc[a][4 * k + 1] = fmaxf(acc[a][4 * k + 1] + b4.y, 0.f);
            acc[a][4 * k + 2] = fmaxf(acc[a][4 * k + 2] + b4.z, 0.f);
            acc[a][4 * k + 3] = fmaxf(acc[a][4 * k + 3] + b4.w, 0.f);
        }
    }

    __syncthreads();   // staging region dead -> per-wave slabs may reuse it

    // ---- phase 2: 4 passes of 2 samples through a per-wave 1536-float slab ----
    const float* Mw  = ws + WS_M;
    const int c0   = 2 * lane;       // phase-2 col pair
    const int slab = w * 1536;       // per-wave, disjoint across waves

    #pragma unroll 1
    for (int p = 0; p < 4; ++p) {
        // write slab: groups 2p, 2p+1 copy their relu'd enc rows
        if ((g >> 1) == p) {
            const int sb = slab + (g & 1) * 768;
            #pragma unroll
            for (int a = 0; a < AG; ++a)
                #pragma unroll
                for (int k = 0; k < 4; ++k) {
                    float4 v = make_float4(acc[a][4 * k], acc[a][4 * k + 1],
                                           acc[a][4 * k + 2], acc[a][4 * k + 3]);
                    *(float4*)&lds[sb + a * DD + 32 * k + 4 * i] = v;
                }
        }
        // (same-wave LDS write->read ordered via lgkmcnt; no barrier needed)

        // t = ag_e @ M for both samples
        float t0[2] = {0.f, 0.f}, t1[2] = {0.f, 0.f};
        #pragma unroll 4
        for (int d = 0; d < DD; d += 4) {
            float4 a0 = *(const float4*)&lds[slab + d];
            float4 a1 = *(const float4*)&lds[slab + 768 + d];
            float2 m0 = *(const float2*)&Mw[(size_t)(d + 0) * DD + c0];
            float2 m1 = *(const float2*)&Mw[(size_t)(d + 1) * DD + c0];
            float2 m2 = *(const float2*)&Mw[(size_t)(d + 2) * DD + c0];
            float2 m3 = *(const float2*)&Mw[(size_t)(d + 3) * DD + c0];
            t0[0] = fmaf(a0.x, m0.x, t0[0]); t1[0] = fmaf(a0.x, m0.y, t1[0]);
            t0[0] = fmaf(a0.y, m1.x, t0[0]); t1[0] = fmaf(a0.y, m1.y, t1[0]);
            t0[0] = fmaf(a0.z, m2.x, t0[0]); t1[0] = fmaf(a0.z, m2.y, t1[0]);
            t0[0] = fmaf(a0.w, m3.x, t0[0]); t1[0] = fmaf(a0.w, m3.y, t1[0]);
            t0[1] = fmaf(a1.x, m0.x, t0[1]); t1[1] = fmaf(a1.x, m0.y, t1[1]);
            t0[1] = fmaf(a1.y, m1.x, t0[1]); t1[1] = fmaf(a1.y, m1.y, t1[1]);
            t0[1] = fmaf(a1.z, m2.x, t0[1]); t1[1] = fmaf(a1.z, m2.y, t1[1]);
            t0[1] = fmaf(a1.w, m3.x, t0[1]); t1[1] = fmaf(a1.w, m3.y, t1[1]);
        }

        // scores (partial over this lane's col pair), then butterfly
        float vx[2][EE], vy[2][EE], sc[2][EE];
        #pragma unroll
        for (int j = 0; j < 2; ++j)
            #pragma unroll
            for (int e = 0; e < EE; ++e) {
                float2 v = *(const float2*)&lds[slab + j * 768 + (1 + e) * DD + c0];
                vx[j][e] = v.x; vy[j][e] = v.y;
                sc[j][e] = t0[j] * v.x + t1[j] * v.y;
            }
        #pragma unroll
        for (int off = 32; off > 0; off >>= 1)
            #pragma unroll
            for (int j = 0; j < 2; ++j)
                #pragma unroll
                for (int e = 0; e < EE; ++e)
                    sc[j][e] += __shfl_xor(sc[j][e], off, 64);

        float alpha[2][EE];
        #pragma unroll
        for (int j = 0; j < 2; ++j) {
            float mx = sc[j][0];
            #pragma unroll
            for (int e = 1; e < EE; ++e) mx = fmaxf(mx, sc[j][e]);
            float sum = 0.f;
            #pragma unroll
            for (int e = 0; e < EE; ++e) { alpha[j][e] = expf(sc[j][e] - mx); sum += alpha[j][e]; }
            const float inv = 1.f / sum;
            #pragma unroll
            for (int e = 0; e < EE; ++e) alpha[j][e] *= inv;
        }

        // logits (partial over col pair), butterfly
        float Lg[2][NOUT];
        #pragma unroll
        for (int j = 0; j < 2; ++j) {
            float2 a2 = *(const float2*)&lds[slab + j * 768 + c0];
            #pragma unroll
            for (int o = 0; o < NOUT; ++o) {
                float2 w1 = *(const float2*)&ws[WS_W1T + o * DD + c0];
                Lg[j][o] = fmaf(a2.x, w1.x, a2.y * w1.y);
            }
        }
        #pragma unroll
        for (int e = 0; e < EE; ++e) {
            float wxj[2], wyj[2];
            #pragma unroll
            for (int j = 0; j < 2; ++j) { wxj[j] = alpha[j][e] * vx[j][e]; wyj[j] = alpha[j][e] * vy[j][e]; }
            #pragma unroll
            for (int o = 0; o < NOUT; ++o) {
                float2 f2 = *(const float2*)&ws[WS_F2T + (e * NOUT + o) * DD + c0];
                #pragma unroll
                for (int j = 0; j < 2; ++j)
                    Lg[j][o] = fmaf(wxj[j], f2.x, fmaf(wyj[j], f2.y, Lg[j][o]));
            }
        }
        #pragma unroll
        for (int off = 32; off > 0; off >>= 1)
            #pragma unroll
            for (int j = 0; j < 2; ++j)
                #pragma unroll
                for (int o = 0; o < NOUT; ++o)
                    Lg[j][o] += __shfl_xor(Lg[j][o], off, 64);

        // Gumbel + argmax (monotone -> skip softmax/tau)
        const int S0 = bs0 + w * 8 + 2 * p;
        float y = -1e30f;
        if (lane < 10) {
            const int jl = lane / 5, ol = lane - 5 * jl;
            const float uu  = u[(size_t)S0 * NOUT + lane];      // contiguous across both samples
            const float gmb = -logf(-logf(uu + 1e-10f) + 1e-10f);
            y = Lg[jl][ol] + fc_b[ol] + gmb;
        }
        float b0 = -1e30f, b1 = -1e30f; int bi0 = 0, bi1 = 0;
        #pragma unroll
        for (int o = 0; o < NOUT; ++o) {
            float y0 = __shfl(y, o, 64);
            float y1 = __shfl(y, 5 + o, 64);
            if (y0 > b0) { b0 = y0; bi0 = o; }   // strict > == np.argmax first-max
            if (y1 > b1) { b1 = y1; bi1 = o; }
        }
        if (lane < 2) out[S0 + lane] = lane ? bi1 : bi0;
    }
}

extern "C" void kernel_launch(void* const* d_in, const int* in_sizes, int n_in,
                              void* d_out, int out_size, void* d_ws, size_t ws_size,
                              hipStream_t stream) {
    const float* obs   = (const float*)d_in[0];
    const float* enc_w = (const float*)d_in[1];
    const float* enc_b = (const float*)d_in[2];
    const float* q_w   = (const float*)d_in[3];
    const float* k_w   = (const float*)d_in[4];
    const float* fc_w  = (const float*)d_in[5];
    const float* fc_b  = (const float*)d_in[6];
    const float* uu    = (const float*)d_in[7];
    float* ws = (float*)d_ws;
    int*   po = (int*)d_out;

    precompute_kernel<<<129, 128, 0, stream>>>(q_w, k_w, fc_w, ws);
    policy_kernel<<<NB / SBLK, 256, 0, stream>>>(obs, enc_w, enc_b, fc_b, uu, ws, po);
}

// Round 4
// 469.070 us; speedup vs baseline: 1.3349x; 1.3349x over previous
//
#include <hip/hip_runtime.h>
#include <math.h>

// Problem constants
#define NB   32768
#define AG   6
#define LL   225
#define DD   128
#define EE   5
#define NOUT 5
#define ADIM 64

// Workspace layout (floats)
#define WS_M   0        // 128*128  : M = q_w @ k_w^T / 8   (row-major [d1][d2])
#define WS_W1T 16384    // 5*128    : W1t[o*128+d] = sum_e fc_w[(e*128+d)*5+o]
#define WS_F2T 17024    // 25*128   : F2t[(e*5+o)*128+d] = fc_w[(640+e*128+d)*5+o]

// Tiling: block = 256 thr = 4 waves; wave = 4 samples (4 groups x 16 lanes);
// lane owns 8 cols: {4i..4i+3} u {64+4i..64+4i+3}, i = lane&15.
#define SBLK 16          // samples per block
#define RWS  96          // obs rows per block = SBLK*AG
#define LC   45          // l-chunk; 5*45 = 225 exactly, no tail chunk
#define NCH  5
#define ENCW_OFF 4320    // 96*45
#define LDS_FLOATS 10080 // 4320 + 45*128 = 40,320 B -> 4 blocks/CU (with VGPR<=128)

__device__ __forceinline__ void glds4(const float* g, const float* l) {
    __builtin_amdgcn_global_load_lds((const __attribute__((address_space(1))) void*)g,
                                     (__attribute__((address_space(3))) void*)l, 4, 0, 0);
}
__device__ __forceinline__ void glds16(const float* g, const float* l) {
    __builtin_amdgcn_global_load_lds((const __attribute__((address_space(1))) void*)g,
                                     (__attribute__((address_space(3))) void*)l, 16, 0, 0);
}

__global__ void precompute_kernel(const float* __restrict__ q_w,
                                  const float* __restrict__ k_w,
                                  const float* __restrict__ fc_w,
                                  float* __restrict__ ws) {
    int b = blockIdx.x;
    int t = threadIdx.x;
    if (b < 128) {
        float s = 0.f;
        #pragma unroll 8
        for (int j = 0; j < ADIM; ++j)
            s = fmaf(q_w[b * ADIM + j], k_w[t * ADIM + j], s);
        ws[WS_M + b * 128 + t] = s * 0.125f;
    } else {
        int d = t;
        #pragma unroll
        for (int o = 0; o < NOUT; ++o) {
            float s = 0.f;
            #pragma unroll
            for (int e = 0; e < EE; ++e)
                s += fc_w[(e * 128 + d) * NOUT + o];
            ws[WS_W1T + o * 128 + d] = s;
            #pragma unroll
            for (int e = 0; e < EE; ++e)
                ws[WS_F2T + (e * 5 + o) * 128 + d] = fc_w[(640 + e * 128 + d) * NOUT + o];
        }
    }
}

__global__ __launch_bounds__(256, 4)
void policy_kernel(const float* __restrict__ obs,
                   const float* __restrict__ enc_w,
                   const float* __restrict__ enc_b,
                   const float* __restrict__ fc_b,
                   const float* __restrict__ u,
                   const float* __restrict__ ws,
                   int* __restrict__ out) {
    __shared__ float lds[LDS_FLOATS];
    const int tid  = threadIdx.x;
    const int lane = tid & 63;
    const int w    = tid >> 6;
    const int g    = lane >> 4;      // sample group 0..3
    const int ii   = lane & 15;      // col sub-index
    const int bs0  = blockIdx.x * SBLK;
    const int samp = w * 4 + g;      // block-local sample
    const int obsrow = samp * AG;    // block-local obs row of agent 0

    float acc[AG][8];                // 48 acc regs; cols {4ii..} and {64+4ii..}
    #pragma unroll
    for (int a = 0; a < AG; ++a)
        #pragma unroll
        for (int c = 0; c < 8; ++c) acc[a][c] = 0.f;

    const float* obs_blk = obs + (size_t)bs0 * (AG * LL);

    #pragma unroll 1
    for (int ch = 0; ch < NCH; ++ch) {
        const int l0 = ch * LC;
        // ---- async stage obs chunk: 96 rows x 45 cols, lds[idx] with idx == row*45+col ----
        #pragma unroll
        for (int k = 0; k < 17; ++k) {           // 4320 = 16*256 + 224
            int idx = k * 256 + tid;
            if (idx < RWS * LC) {
                int row = idx / LC;              // magic-mul div
                int col = idx - row * LC;
                glds4(&obs_blk[row * LL + l0 + col], &lds[k * 256 + 64 * w]);
            }
        }
        // ---- async stage enc_w chunk: 45 x 128 floats as float4 ----
        #pragma unroll
        for (int k = 0; k < 6; ++k) {            // 1440 = 5*256 + 160
            int f = k * 256 + tid;
            if (f < (LC * DD) / 4)
                glds16(&enc_w[(size_t)l0 * DD + 4 * f],
                       &lds[ENCW_OFF + 4 * (k * 256 + 64 * w)]);
        }
        __syncthreads();   // compiler drains vmcnt before the barrier

        // ---- compute: 11 l-quads + 1 tail l (45 = 11*4 + 1) ----
        #pragma unroll 1
        for (int q = 0; q < 11; ++q) {
            const int lq = 4 * q;
            float ew[4][8];
            #pragma unroll
            for (int dl = 0; dl < 4; ++dl) {
                float4 lo = *(const float4*)&lds[ENCW_OFF + (lq + dl) * DD + 4 * ii];
                float4 hi = *(const float4*)&lds[ENCW_OFF + (lq + dl) * DD + 64 + 4 * ii];
                ew[dl][0] = lo.x; ew[dl][1] = lo.y; ew[dl][2] = lo.z; ew[dl][3] = lo.w;
                ew[dl][4] = hi.x; ew[dl][5] = hi.y; ew[dl][6] = hi.z; ew[dl][7] = hi.w;
            }
            #pragma unroll
            for (int a = 0; a < AG; ++a) {
                float4 ov4 = *(const float4*)&lds[(obsrow + a) * LC + lq];
                float ov[4] = {ov4.x, ov4.y, ov4.z, ov4.w};
                #pragma unroll
                for (int dl = 0; dl < 4; ++dl)
                    #pragma unroll
                    for (int c = 0; c < 8; ++c)
                        acc[a][c] = fmaf(ov[dl], ew[dl][c], acc[a][c]);
            }
        }
        {   // tail l = 44 of this chunk
            float4 lo = *(const float4*)&lds[ENCW_OFF + 44 * DD + 4 * ii];
            float4 hi = *(const float4*)&lds[ENCW_OFF + 44 * DD + 64 + 4 * ii];
            float ewt[8] = {lo.x, lo.y, lo.z, lo.w, hi.x, hi.y, hi.z, hi.w};
            #pragma unroll
            for (int a = 0; a < AG; ++a) {
                float ov = lds[(obsrow + a) * LC + 44];
                #pragma unroll
                for (int c = 0; c < 8; ++c)
                    acc[a][c] = fmaf(ov, ewt[c], acc[a][c]);
            }
        }
        __syncthreads();   // chunk data dead; also guards phase-2 LDS reuse after loop
    }

    // ---- bias + relu in place ----
    {
        float4 bl = *(const float4*)&enc_b[4 * ii];
        float4 bh = *(const float4*)&enc_b[64 + 4 * ii];
        #pragma unroll
        for (int a = 0; a < AG; ++a) {
            acc[a][0] = fmaxf(acc[a][0] + bl.x, 0.f);
            acc[a][1] = fmaxf(acc[a][1] + bl.y, 0.f);
            acc[a][2] = fmaxf(acc[a][2] + bl.z, 0.f);
            acc[a][3] = fmaxf(acc[a][3] + bl.w, 0.f);
            acc[a][4] = fmaxf(acc[a][4] + bh.x, 0.f);
            acc[a][5] = fmaxf(acc[a][5] + bh.y, 0.f);
            acc[a][6] = fmaxf(acc[a][6] + bh.z, 0.f);
            acc[a][7] = fmaxf(acc[a][7] + bh.w, 0.f);
        }
    }

    // ---- phase 2: 2 passes of 2 samples through a per-wave 1536-float slab ----
    const float* Mw  = ws + WS_M;
    const int c0   = 2 * lane;       // phase-2 col pair
    const int slab = w * 1536;       // per-wave slab, reuses dead staging LDS

    #pragma unroll 1
    for (int p = 0; p < 2; ++p) {
        // groups 2p, 2p+1 publish their relu'd enc rows
        if ((g >> 1) == p) {
            const int sb = slab + (g & 1) * 768;
            #pragma unroll
            for (int a = 0; a < AG; ++a) {
                *(float4*)&lds[sb + a * DD + 4 * ii] =
                    make_float4(acc[a][0], acc[a][1], acc[a][2], acc[a][3]);
                *(float4*)&lds[sb + a * DD + 64 + 4 * ii] =
                    make_float4(acc[a][4], acc[a][5], acc[a][6], acc[a][7]);
            }
        }
        // same-wave LDS write->read ordered via lgkmcnt; no barrier needed

        // t = ag_e @ M for both samples
        float t0[2] = {0.f, 0.f}, t1[2] = {0.f, 0.f};
        #pragma unroll 4
        for (int d = 0; d < DD; d += 4) {
            float4 a0 = *(const float4*)&lds[slab + d];
            float4 a1 = *(const float4*)&lds[slab + 768 + d];
            float2 m0 = *(const float2*)&Mw[(size_t)(d + 0) * DD + c0];
            float2 m1 = *(const float2*)&Mw[(size_t)(d + 1) * DD + c0];
            float2 m2 = *(const float2*)&Mw[(size_t)(d + 2) * DD + c0];
            float2 m3 = *(const float2*)&Mw[(size_t)(d + 3) * DD + c0];
            t0[0] = fmaf(a0.x, m0.x, t0[0]); t1[0] = fmaf(a0.x, m0.y, t1[0]);
            t0[0] = fmaf(a0.y, m1.x, t0[0]); t1[0] = fmaf(a0.y, m1.y, t1[0]);
            t0[0] = fmaf(a0.z, m2.x, t0[0]); t1[0] = fmaf(a0.z, m2.y, t1[0]);
            t0[0] = fmaf(a0.w, m3.x, t0[0]); t1[0] = fmaf(a0.w, m3.y, t1[0]);
            t0[1] = fmaf(a1.x, m0.x, t0[1]); t1[1] = fmaf(a1.x, m0.y, t1[1]);
            t0[1] = fmaf(a1.y, m1.x, t0[1]); t1[1] = fmaf(a1.y, m1.y, t1[1]);
            t0[1] = fmaf(a1.z, m2.x, t0[1]); t1[1] = fmaf(a1.z, m2.y, t1[1]);
            t0[1] = fmaf(a1.w, m3.x, t0[1]); t1[1] = fmaf(a1.w, m3.y, t1[1]);
        }

        // scores (partial over this lane's col pair), then butterfly
        float vx[2][EE], vy[2][EE], sc[2][EE];
        #pragma unroll
        for (int j = 0; j < 2; ++j)
            #pragma unroll
            for (int e = 0; e < EE; ++e) {
                float2 v = *(const float2*)&lds[slab + j * 768 + (1 + e) * DD + c0];
                vx[j][e] = v.x; vy[j][e] = v.y;
                sc[j][e] = t0[j] * v.x + t1[j] * v.y;
            }
        #pragma unroll
        for (int off = 32; off > 0; off >>= 1)
            #pragma unroll
            for (int j = 0; j < 2; ++j)
                #pragma unroll
                for (int e = 0; e < EE; ++e)
                    sc[j][e] += __shfl_xor(sc[j][e], off, 64);

        float alpha[2][EE];
        #pragma unroll
        for (int j = 0; j < 2; ++j) {
            float mx = sc[j][0];
            #pragma unroll
            for (int e = 1; e < EE; ++e) mx = fmaxf(mx, sc[j][e]);
            float sum = 0.f;
            #pragma unroll
            for (int e = 0; e < EE; ++e) { alpha[j][e] = expf(sc[j][e] - mx); sum += alpha[j][e]; }
            const float inv = 1.f / sum;
            #pragma unroll
            for (int e = 0; e < EE; ++e) alpha[j][e] *= inv;
        }

        // logits (partial over col pair), butterfly
        float Lg[2][NOUT];
        #pragma unroll
        for (int j = 0; j < 2; ++j) {
            float2 a2 = *(const float2*)&lds[slab + j * 768 + c0];
            #pragma unroll
            for (int o = 0; o < NOUT; ++o) {
                float2 w1 = *(const float2*)&ws[WS_W1T + o * DD + c0];
                Lg[j][o] = fmaf(a2.x, w1.x, a2.y * w1.y);
            }
        }
        #pragma unroll
        for (int e = 0; e < EE; ++e) {
            float wxj[2], wyj[2];
            #pragma unroll
            for (int j = 0; j < 2; ++j) { wxj[j] = alpha[j][e] * vx[j][e]; wyj[j] = alpha[j][e] * vy[j][e]; }
            #pragma unroll
            for (int o = 0; o < NOUT; ++o) {
                float2 f2 = *(const float2*)&ws[WS_F2T + (e * NOUT + o) * DD + c0];
                #pragma unroll
                for (int j = 0; j < 2; ++j)
                    Lg[j][o] = fmaf(wxj[j], f2.x, fmaf(wyj[j], f2.y, Lg[j][o]));
            }
        }
        #pragma unroll
        for (int off = 32; off > 0; off >>= 1)
            #pragma unroll
            for (int j = 0; j < 2; ++j)
                #pragma unroll
                for (int o = 0; o < NOUT; ++o)
                    Lg[j][o] += __shfl_xor(Lg[j][o], off, 64);

        // Gumbel + argmax (monotone -> skip softmax/tau)
        const int S0 = bs0 + w * 4 + 2 * p;
        float y = -1e30f;
        if (lane < 10) {
            const int jl = lane / 5, ol = lane - 5 * jl;
            const float uu  = u[(size_t)S0 * NOUT + lane];      // contiguous over both samples
            const float gmb = -logf(-logf(uu + 1e-10f) + 1e-10f);
            y = Lg[jl][ol] + fc_b[ol] + gmb;
        }
        float b0 = -1e30f, b1 = -1e30f; int bi0 = 0, bi1 = 0;
        #pragma unroll
        for (int o = 0; o < NOUT; ++o) {
            float y0 = __shfl(y, o, 64);
            float y1 = __shfl(y, 5 + o, 64);
            if (y0 > b0) { b0 = y0; bi0 = o; }   // strict > == np.argmax first-max
            if (y1 > b1) { b1 = y1; bi1 = o; }
        }
        if (lane < 2) out[S0 + lane] = lane ? bi1 : bi0;
    }
}

extern "C" void kernel_launch(void* const* d_in, const int* in_sizes, int n_in,
                              void* d_out, int out_size, void* d_ws, size_t ws_size,
                              hipStream_t stream) {
    const float* obs   = (const float*)d_in[0];
    const float* enc_w = (const float*)d_in[1];
    const float* enc_b = (const float*)d_in[2];
    const float* q_w   = (const float*)d_in[3];
    const float* k_w   = (const float*)d_in[4];
    const float* fc_w  = (const float*)d_in[5];
    const float* fc_b  = (const float*)d_in[6];
    const float* uu    = (const float*)d_in[7];
    float* ws = (float*)d_ws;
    int*   po = (int*)d_out;

    precompute_kernel<<<129, 128, 0, stream>>>(q_w, k_w, fc_w, ws);
    policy_kernel<<<NB / SBLK, 256, 0, stream>>>(obs, enc_w, enc_b, fc_b, uu, ws, po);
}